// Round 4
// baseline (1976.792 us; speedup 1.0000x reference)
//
#include <hip/hip_runtime.h>

#define N_NODES 100000
#define E_EDGES 1600000
#define E4 (E_EDGES / 4)          // 400000
#define NBUCKETS ((N_NODES + 127) / 128)   // 782

// ---------------------------------------------------------------------------
// GEMM v2: H[N,DOUT] = act(X)[N,64] @ W[64,DOUT]
// 128-row tile, 256 threads, 4x8 acc/thread, all-b128 LDS, swizzled X.
// ---------------------------------------------------------------------------
template<int DOUT, bool RELU_IN>
__global__ __launch_bounds__(256) void gemm_tile2(const float* __restrict__ X,
                                                  const float* __restrict__ W,
                                                  float* __restrict__ H) {
    __shared__ float Xs[128 * 64];   // swizzled: (r,k) at Xs[r*64 + ((k>>2)^((r>>2)&7))*4 + (k&3)]
    __shared__ float Ws[64 * 64];    // plain row-major, zero-padded cols if DOUT<64
    const int tid = threadIdx.x;
    const int row0 = blockIdx.x * 128;

    if (DOUT == 64) {
        for (int i = tid; i < 1024; i += 256)
            reinterpret_cast<float4*>(Ws)[i] = reinterpret_cast<const float4*>(W)[i];
    } else {
        for (int i = tid; i < 4096; i += 256) {
            int k = i >> 6, c = i & 63;
            Ws[i] = (c < DOUT) ? W[k * DOUT + c] : 0.f;
        }
    }

#pragma unroll
    for (int p = 0; p < 8; ++p) {
        int idx = p * 256 + tid;      // 0..2047 float4s
        int r = idx >> 4;             // 0..127
        int cg = idx & 15;            // col-group (4 floats)
        float4 v = make_float4(0.f, 0.f, 0.f, 0.f);
        int gr = row0 + r;
        if (gr < N_NODES) v = *reinterpret_cast<const float4*>(X + (size_t)gr * 64 + cg * 4);
        if (RELU_IN) {
            v.x = fmaxf(v.x, 0.f); v.y = fmaxf(v.y, 0.f);
            v.z = fmaxf(v.z, 0.f); v.w = fmaxf(v.w, 0.f);
        }
        int scg = cg ^ ((r >> 2) & 7);
        *reinterpret_cast<float4*>(Xs + r * 64 + scg * 4) = v;
    }
    __syncthreads();

    const int tcg = tid & 7;          // col group -> 8 cols
    const int trg = tid >> 3;         // row group -> 4 rows
    const int tc = tcg * 8;
    const int tr = trg * 4;
    const int sw = trg & 7;

    float acc[4][8];
#pragma unroll
    for (int i = 0; i < 4; ++i)
#pragma unroll
        for (int j = 0; j < 8; ++j) acc[i][j] = 0.f;

#pragma unroll
    for (int kb = 0; kb < 16; ++kb) {
        float4 xf[4];
#pragma unroll
        for (int i = 0; i < 4; ++i)
            xf[i] = *reinterpret_cast<const float4*>(Xs + (tr + i) * 64 + ((kb ^ sw) * 4));
        float wrow[4][8];
#pragma unroll
        for (int kk = 0; kk < 4; ++kk) {
            float4 a = *reinterpret_cast<const float4*>(Ws + (kb * 4 + kk) * 64 + tc);
            float4 bq = *reinterpret_cast<const float4*>(Ws + (kb * 4 + kk) * 64 + tc + 4);
            wrow[kk][0] = a.x; wrow[kk][1] = a.y; wrow[kk][2] = a.z; wrow[kk][3] = a.w;
            wrow[kk][4] = bq.x; wrow[kk][5] = bq.y; wrow[kk][6] = bq.z; wrow[kk][7] = bq.w;
        }
#pragma unroll
        for (int i = 0; i < 4; ++i) {
#pragma unroll
            for (int j = 0; j < 8; ++j) {
                acc[i][j] += xf[i].x * wrow[0][j] + xf[i].y * wrow[1][j]
                           + xf[i].z * wrow[2][j] + xf[i].w * wrow[3][j];
            }
        }
    }

    if (tc < DOUT) {
#pragma unroll
        for (int i = 0; i < 4; ++i) {
            int gr = row0 + tr + i;
            if (gr < N_NODES) {
                *reinterpret_cast<float4*>(H + (size_t)gr * DOUT + tc) =
                    make_float4(acc[i][0], acc[i][1], acc[i][2], acc[i][3]);
                *reinterpret_cast<float4*>(H + (size_t)gr * DOUT + tc + 4) =
                    make_float4(acc[i][4], acc[i][5], acc[i][6], acc[i][7]);
            }
        }
    }
}

// ---------------------------------------------------------------------------
// Bucketed CSR build. bucket = dst >> 7 (128 nodes per bucket).
// ---------------------------------------------------------------------------
__global__ __launch_bounds__(256) void bucket_hist(const int4* __restrict__ dst4,
                                                   int* __restrict__ bhist) {
    __shared__ int lh[NBUCKETS];
    for (int i = threadIdx.x; i < NBUCKETS; i += 256) lh[i] = 0;
    __syncthreads();
    const int gtid = blockIdx.x * 256 + threadIdx.x;
    const int stride = gridDim.x * 256;
    for (int i = gtid; i < E4; i += stride) {
        int4 d = dst4[i];
        atomicAdd(&lh[d.x >> 7], 1);
        atomicAdd(&lh[d.y >> 7], 1);
        atomicAdd(&lh[d.z >> 7], 1);
        atomicAdd(&lh[d.w >> 7], 1);
    }
    __syncthreads();
    for (int i = threadIdx.x; i < NBUCKETS; i += 256)
        if (lh[i]) atomicAdd(&bhist[i], lh[i]);
}

// single block: exclusive scan of 782 bucket counts -> boff[0..782]
__global__ __launch_bounds__(256) void bucket_scan(const int* __restrict__ bhist,
                                                   int* __restrict__ boff,
                                                   int* __restrict__ off) {
    __shared__ int wsum[4];
    const int tid = threadIdx.x, lane = tid & 63, wv = tid >> 6;
    const int base = tid * 4;
    int v[4];
    int s = 0;
#pragma unroll
    for (int j = 0; j < 4; ++j) {
        v[j] = (base + j < NBUCKETS) ? bhist[base + j] : 0;
        s += v[j];
    }
    int inc = s;
#pragma unroll
    for (int o = 1; o < 64; o <<= 1) {
        int t = __shfl_up(inc, o, 64);
        if (lane >= o) inc += t;
    }
    if (lane == 63) wsum[wv] = inc;
    __syncthreads();
    int woff = 0;
    for (int w2 = 0; w2 < wv; ++w2) woff += wsum[w2];
    int run = woff + inc - s;
#pragma unroll
    for (int j = 0; j < 4; ++j) {
        if (base + j <= NBUCKETS) boff[base + j] = run;
        run += v[j];
    }
    if (tid == 0) off[N_NODES] = E_EDGES;
}

// scatter edges to bucket-contiguous tmp regions (packed: src | dst_local<<17, weight)
__global__ __launch_bounds__(256) void bucket_scatter(const int4* __restrict__ src4,
                                                      const int4* __restrict__ dst4,
                                                      const float4* __restrict__ ew4,
                                                      int* __restrict__ gcur,
                                                      int2* __restrict__ tmp) {
    const int i = blockIdx.x * 256 + threadIdx.x;
    if (i < E4) {
        int4 s = src4[i];
        int4 d = dst4[i];
        float4 w = ew4[i];
        int p0 = atomicAdd(&gcur[d.x >> 7], 1);
        tmp[p0] = make_int2(s.x | ((d.x & 127) << 17), __float_as_int(w.x));
        int p1 = atomicAdd(&gcur[d.y >> 7], 1);
        tmp[p1] = make_int2(s.y | ((d.y & 127) << 17), __float_as_int(w.y));
        int p2 = atomicAdd(&gcur[d.z >> 7], 1);
        tmp[p2] = make_int2(s.z | ((d.z & 127) << 17), __float_as_int(w.z));
        int p3 = atomicAdd(&gcur[d.w >> 7], 1);
        tmp[p3] = make_int2(s.w | ((d.w & 127) << 17), __float_as_int(w.w));
    }
}

// one block per bucket: LDS hist over 128 dst_locals, scan -> per-dst offsets,
// then scatter into final per-dst CSR (block-local 16KB output window).
__global__ __launch_bounds__(256) void build_csr(const int2* __restrict__ tmp,
                                                 const int* __restrict__ boff,
                                                 int* __restrict__ off,
                                                 int2* __restrict__ csr) {
    __shared__ int lhist[128];
    __shared__ int lcur[128];
    __shared__ int wtot[2];
    const int b = blockIdx.x;
    const int tid = threadIdx.x;
    const int base = boff[b];
    const int end  = boff[b + 1];

    if (tid < 128) lhist[tid] = 0;
    __syncthreads();

    for (int e = base + tid; e < end; e += 256) {
        int dl = (tmp[e].x >> 17) & 127;
        atomicAdd(&lhist[dl], 1);
    }
    __syncthreads();

    if (tid < 128) {
        const int lane = tid & 63, wv = tid >> 6;
        int v = lhist[tid];
        int inc = v;
#pragma unroll
        for (int o = 1; o < 64; o <<= 1) {
            int t = __shfl_up(inc, o, 64);
            if (lane >= o) inc += t;
        }
        if (lane == 63) wtot[wv] = inc;
        __syncthreads();
        int excl = inc - v + ((tid >= 64) ? wtot[0] : 0);
        lcur[tid] = base + excl;
        int node = b * 128 + tid;
        if (node < N_NODES) off[node] = base + excl;
    } else {
        __syncthreads();
    }
    __syncthreads();

    for (int e = base + tid; e < end; e += 256) {
        int2 t2 = tmp[e];
        int dl = (t2.x >> 17) & 127;
        int p = atomicAdd(&lcur[dl], 1);
        csr[p] = make_int2(t2.x & 0x1FFFF, t2.y);
    }
}

// ---------------------------------------------------------------------------
// Aggregate: one wave per dst node, lane = channel, unroll-4 gathers.
// ---------------------------------------------------------------------------
template<int DOUT>
__global__ __launch_bounds__(256) void aggregate(const float* __restrict__ H,
                                                 const int* __restrict__ off,
                                                 const int2* __restrict__ csr,
                                                 const float* __restrict__ bvec,
                                                 float* __restrict__ AGG) {
    const int node = (int)((blockIdx.x * 256 + threadIdx.x) >> 6);
    const int lane = threadIdx.x & 63;
    if (node >= N_NODES) return;
    const int k0 = __builtin_amdgcn_readfirstlane(off[node]);
    const int k1 = __builtin_amdgcn_readfirstlane(off[node + 1]);
    const bool active = (DOUT == 64) || (lane < DOUT);
    float acc = active ? bvec[lane] : 0.f;
    int k = k0;
    for (; k + 3 < k1; k += 4) {
        int2 e0 = csr[k], e1 = csr[k + 1], e2 = csr[k + 2], e3 = csr[k + 3];
        int s0 = __builtin_amdgcn_readfirstlane(e0.x);
        int s1 = __builtin_amdgcn_readfirstlane(e1.x);
        int s2 = __builtin_amdgcn_readfirstlane(e2.x);
        int s3 = __builtin_amdgcn_readfirstlane(e3.x);
        float h0 = 0.f, h1 = 0.f, h2 = 0.f, h3 = 0.f;
        if (active) {
            h0 = H[(size_t)s0 * DOUT + lane];
            h1 = H[(size_t)s1 * DOUT + lane];
            h2 = H[(size_t)s2 * DOUT + lane];
            h3 = H[(size_t)s3 * DOUT + lane];
        }
        acc += h0 * __int_as_float(e0.y) + h1 * __int_as_float(e1.y)
             + h2 * __int_as_float(e2.y) + h3 * __int_as_float(e3.y);
    }
    for (; k < k1; ++k) {
        int2 e0 = csr[k];
        int s0 = __builtin_amdgcn_readfirstlane(e0.x);
        if (active) acc += H[(size_t)s0 * DOUT + lane] * __int_as_float(e0.y);
    }
    if (active) AGG[(size_t)node * DOUT + lane] = acc;
}

// ---------------------------------------------------------------------------
extern "C" void kernel_launch(void* const* d_in, const int* in_sizes, int n_in,
                              void* d_out, int out_size, void* d_ws, size_t ws_size,
                              hipStream_t stream) {
    const float* x    = (const float*)d_in[0];
    const float* ew   = (const float*)d_in[1];
    const float* W    = (const float*)d_in[2];   // [4,64,64]
    const float* b    = (const float*)d_in[3];   // [4,64]
    const float* Wout = (const float*)d_in[4];   // [64,40]
    const float* bout = (const float*)d_in[5];   // [40]
    const int*   src  = (const int*)d_in[6];
    const int*   dst  = (const int*)d_in[7];
    float* out = (float*)d_out;

    // workspace layout (csr_tmp aliases H: consumed by build_csr before gemm0 writes H)
    float* H    = (float*)d_ws;                              // N*64 f  (25.6 MB)
    float* AGG  = H + (size_t)N_NODES * 64;                  // N*64 f  (25.6 MB)
    int2*  csr  = (int2*)(AGG + (size_t)N_NODES * 64);       // E int2  (12.8 MB)
    int*   off  = (int*)(csr + E_EDGES);                     // N+1
    int*   bhist= off + N_NODES + 1;                         // NBUCKETS
    int*   boff = bhist + NBUCKETS;                          // NBUCKETS+1
    int*   gcur = boff + NBUCKETS + 1;                       // NBUCKETS
    int2*  csr_tmp = (int2*)H;                               // alias (12.8 MB < 25.6 MB)

    dim3 blk(256);
    const int gemmGrid = (N_NODES + 127) / 128;              // 782
    const int aggGrid  = (N_NODES * 64 + 255) / 256;         // 25000

    // ---- build bucketed CSR (once; reused by all 5 layers) ----
    hipMemsetAsync(bhist, 0, NBUCKETS * sizeof(int), stream);
    bucket_hist<<<391, blk, 0, stream>>>((const int4*)dst, bhist);
    bucket_scan<<<1, blk, 0, stream>>>(bhist, boff, off);
    hipMemcpyAsync(gcur, boff, NBUCKETS * sizeof(int), hipMemcpyDeviceToDevice, stream);
    bucket_scatter<<<(E4 + 255) / 256, blk, 0, stream>>>((const int4*)src, (const int4*)dst,
                                                         (const float4*)ew, gcur, csr_tmp);
    build_csr<<<NBUCKETS, blk, 0, stream>>>(csr_tmp, boff, off, csr);

    // ---- layer 0 ----
    gemm_tile2<64, false><<<gemmGrid, blk, 0, stream>>>(x, W, H);
    aggregate<64><<<aggGrid, blk, 0, stream>>>(H, off, csr, b, AGG);

    // ---- layers 1..3 ----
    for (int i = 1; i < 4; ++i) {
        gemm_tile2<64, true><<<gemmGrid, blk, 0, stream>>>(AGG, W + (size_t)i * 64 * 64, H);
        aggregate<64><<<aggGrid, blk, 0, stream>>>(H, off, csr, b + (size_t)i * 64, AGG);
    }

    // ---- final layer -> d_out [N,40] ----
    gemm_tile2<40, true><<<gemmGrid, blk, 0, stream>>>(AGG, Wout, H);
    aggregate<40><<<aggGrid, blk, 0, stream>>>(H, off, csr, bout, out);
}

// Round 5
// 383.591 us; speedup vs baseline: 5.1534x; 5.1534x over previous
//
#include <hip/hip_runtime.h>
#include <hip/hip_fp16.h>

#define N_NODES 100000
#define E_EDGES 1600000
#define E4 (E_EDGES / 4)                       // 400000
#define NBUCKETS ((N_NODES + 127) / 128)       // 782
#define CHUNK 8192
#define NCHUNK ((E_EDGES + CHUNK - 1) / CHUNK) // 196
#define HM (NBUCKETS * NCHUNK)                 // 153272
#define NSB ((HM + 1023) / 1024)               // 150

// ---------------------------------------------------------------------------
// GEMM (round-3 proven): H[N,DOUT] = act(X)[N,64] @ W[64,DOUT], fp16 output
// ---------------------------------------------------------------------------
template<int DOUT, bool RELU_IN>
__global__ __launch_bounds__(256) void gemm_tile(const float* __restrict__ X,
                                                 const float* __restrict__ W,
                                                 __half* __restrict__ H) {
    __shared__ float Xs[64][68];
    __shared__ float Ws[64 * DOUT];
    const int tid = threadIdx.x;

    for (int i = tid; i < 64 * DOUT / 4; i += 256) {
        reinterpret_cast<float4*>(Ws)[i] = reinterpret_cast<const float4*>(W)[i];
    }

    const int row0 = blockIdx.x * 64;
#pragma unroll
    for (int p = 0; p < 4; ++p) {
        int idx = p * 256 + tid;
        int r = idx >> 4;
        int c = (idx & 15) << 2;
        float4 v = make_float4(0.f, 0.f, 0.f, 0.f);
        if (row0 + r < N_NODES) {
            v = *reinterpret_cast<const float4*>(X + (size_t)(row0 + r) * 64 + c);
        }
        if (RELU_IN) {
            v.x = fmaxf(v.x, 0.f); v.y = fmaxf(v.y, 0.f);
            v.z = fmaxf(v.z, 0.f); v.w = fmaxf(v.w, 0.f);
        }
        *reinterpret_cast<float4*>(&Xs[r][c]) = v;
    }
    __syncthreads();

    const int tr = (tid >> 4) << 2;
    const int tc = (tid & 15) << 2;
    if (tc < DOUT) {
        float acc[4][4];
#pragma unroll
        for (int i = 0; i < 4; ++i)
#pragma unroll
            for (int j = 0; j < 4; ++j) acc[i][j] = 0.f;

#pragma unroll 8
        for (int k = 0; k < 64; ++k) {
            float4 wv = *reinterpret_cast<const float4*>(&Ws[k * DOUT + tc]);
            float xv[4];
#pragma unroll
            for (int i = 0; i < 4; ++i) xv[i] = Xs[tr + i][k];
#pragma unroll
            for (int i = 0; i < 4; ++i) {
                acc[i][0] += xv[i] * wv.x;
                acc[i][1] += xv[i] * wv.y;
                acc[i][2] += xv[i] * wv.z;
                acc[i][3] += xv[i] * wv.w;
            }
        }
#pragma unroll
        for (int i = 0; i < 4; ++i) {
            int r = row0 + tr + i;
            if (r < N_NODES) {
                union { __half2 h2[2]; uint2 u; } pk;
                pk.h2[0] = __halves2half2(__float2half(acc[i][0]), __float2half(acc[i][1]));
                pk.h2[1] = __halves2half2(__float2half(acc[i][2]), __float2half(acc[i][3]));
                *reinterpret_cast<uint2*>(H + (size_t)r * DOUT + tc) = pk.u;
            }
        }
    }
}

// ---------------------------------------------------------------------------
// CSR build v3: chunked counting sort, NO global atomics.
// ---------------------------------------------------------------------------
__global__ __launch_bounds__(256) void chunk_hist(const int4* __restrict__ dst4,
                                                  int* __restrict__ histM) {
    __shared__ int lh[NBUCKETS];
    const int tid = threadIdx.x, c = blockIdx.x;
    for (int i = tid; i < NBUCKETS; i += 256) lh[i] = 0;
    __syncthreads();
    const int q0 = c * (CHUNK / 4);
    for (int q = tid; q < CHUNK / 4; q += 256) {
        if (q0 + q < E4) {
            int4 d = dst4[q0 + q];
            atomicAdd(&lh[d.x >> 7], 1);
            atomicAdd(&lh[d.y >> 7], 1);
            atomicAdd(&lh[d.z >> 7], 1);
            atomicAdd(&lh[d.w >> 7], 1);
        }
    }
    __syncthreads();
    for (int i = tid; i < NBUCKETS; i += 256) histM[i * NCHUNK + c] = lh[i];
}

// exclusive scan of histM (HM elems) -> hs; per-1024 chunks + block sums
__global__ __launch_bounds__(256) void scan_blocks(const int* __restrict__ in,
                                                   int* __restrict__ out,
                                                   int* __restrict__ bsums) {
    __shared__ int wsum[4];
    const int tid = threadIdx.x, lane = tid & 63, wv = tid >> 6;
    const int base = blockIdx.x * 1024 + tid * 4;
    int v[4];
    int s = 0;
#pragma unroll
    for (int j = 0; j < 4; ++j) {
        v[j] = (base + j < HM) ? in[base + j] : 0;
        s += v[j];
    }
    int inc = s;
#pragma unroll
    for (int o = 1; o < 64; o <<= 1) {
        int t = __shfl_up(inc, o, 64);
        if (lane >= o) inc += t;
    }
    if (lane == 63) wsum[wv] = inc;
    __syncthreads();
    int woff = 0;
    for (int w2 = 0; w2 < wv; ++w2) woff += wsum[w2];
    int run = woff + inc - s;
#pragma unroll
    for (int j = 0; j < 4; ++j) {
        if (base + j < HM) out[base + j] = run;
        run += v[j];
    }
    if (tid == 255) bsums[blockIdx.x] = woff + inc;
}

__global__ __launch_bounds__(256) void scan_mid256(const int* __restrict__ bs,
                                                   int* __restrict__ boff) {
    __shared__ int wsum[4];
    const int tid = threadIdx.x, lane = tid & 63, wv = tid >> 6;
    int v = (tid < NSB) ? bs[tid] : 0;
    int inc = v;
#pragma unroll
    for (int o = 1; o < 64; o <<= 1) {
        int t = __shfl_up(inc, o, 64);
        if (lane >= o) inc += t;
    }
    if (lane == 63) wsum[wv] = inc;
    __syncthreads();
    int woff = 0;
    for (int w2 = 0; w2 < wv; ++w2) woff += wsum[w2];
    if (tid < NSB) boff[tid] = woff + inc - v;
}

__global__ __launch_bounds__(256) void scan_add(int* __restrict__ out,
                                                const int* __restrict__ boff) {
    const int base = blockIdx.x * 1024 + threadIdx.x * 4;
    const int a = boff[blockIdx.x];
#pragma unroll
    for (int j = 0; j < 4; ++j) {
        if (base + j < HM) out[base + j] += a;
    }
}

// scatter edges into bucket-grouped tmp using precomputed (bucket,chunk) bases
__global__ __launch_bounds__(256) void chunk_scatter(const int4* __restrict__ src4,
                                                     const int4* __restrict__ dst4,
                                                     const float4* __restrict__ ew4,
                                                     const int* __restrict__ hs,
                                                     int2* __restrict__ tmp) {
    __shared__ int lcur[NBUCKETS];
    const int tid = threadIdx.x, c = blockIdx.x;
    for (int i = tid; i < NBUCKETS; i += 256) lcur[i] = hs[i * NCHUNK + c];
    __syncthreads();
    const int q0 = c * (CHUNK / 4);
    for (int q = tid; q < CHUNK / 4; q += 256) {
        if (q0 + q < E4) {
            int4 s = src4[q0 + q];
            int4 d = dst4[q0 + q];
            float4 w = ew4[q0 + q];
            int p0 = atomicAdd(&lcur[d.x >> 7], 1);
            tmp[p0] = make_int2(s.x | ((d.x & 127) << 17), __float_as_int(w.x));
            int p1 = atomicAdd(&lcur[d.y >> 7], 1);
            tmp[p1] = make_int2(s.y | ((d.y & 127) << 17), __float_as_int(w.y));
            int p2 = atomicAdd(&lcur[d.z >> 7], 1);
            tmp[p2] = make_int2(s.z | ((d.z & 127) << 17), __float_as_int(w.z));
            int p3 = atomicAdd(&lcur[d.w >> 7], 1);
            tmp[p3] = make_int2(s.w | ((d.w & 127) << 17), __float_as_int(w.w));
        }
    }
}

// one block per bucket: LDS hist over 128 dst-locals, scan, scatter to final CSR
__global__ __launch_bounds__(256) void build_csr(const int2* __restrict__ tmp,
                                                 const int* __restrict__ hs,
                                                 int* __restrict__ off,
                                                 int2* __restrict__ csr) {
    __shared__ int lhist[128];
    __shared__ int lcur[128];
    __shared__ int wtot[4];
    const int b = blockIdx.x;
    const int tid = threadIdx.x, lane = tid & 63, wv = tid >> 6;
    const int base = hs[b * NCHUNK];
    const int end  = (b + 1 < NBUCKETS) ? hs[(b + 1) * NCHUNK] : E_EDGES;

    if (tid < 128) lhist[tid] = 0;
    __syncthreads();

    for (int e = base + tid; e < end; e += 256) {
        int dl = (tmp[e].x >> 17) & 127;
        atomicAdd(&lhist[dl], 1);
    }
    __syncthreads();

    int v = (tid < 128) ? lhist[tid] : 0;
    int inc = v;
#pragma unroll
    for (int o = 1; o < 64; o <<= 1) {
        int t = __shfl_up(inc, o, 64);
        if (lane >= o) inc += t;
    }
    if (lane == 63) wtot[wv] = inc;
    __syncthreads();
    if (tid < 128) {
        int excl = inc - v + ((wv == 1) ? wtot[0] : 0);
        lcur[tid] = base + excl;
        int node = b * 128 + tid;
        if (node < N_NODES) off[node] = base + excl;
    }
    if (b == NBUCKETS - 1 && tid == 0) off[N_NODES] = E_EDGES;
    __syncthreads();

    for (int e = base + tid; e < end; e += 256) {
        int2 t2 = tmp[e];
        int dl = (t2.x >> 17) & 127;
        int p = atomicAdd(&lcur[dl], 1);
        csr[p] = make_int2(t2.x & 0x1FFFF, t2.y);
    }
}

// ---------------------------------------------------------------------------
// Aggregate: one wave per dst node, lane = channel, unroll-4 fp16 gathers.
// ---------------------------------------------------------------------------
template<int DOUT>
__global__ __launch_bounds__(256) void aggregate(const __half* __restrict__ H,
                                                 const int* __restrict__ off,
                                                 const int2* __restrict__ csr,
                                                 const float* __restrict__ bvec,
                                                 float* __restrict__ AGG) {
    const int node = (int)((blockIdx.x * 256 + threadIdx.x) >> 6);
    const int lane = threadIdx.x & 63;
    if (node >= N_NODES) return;
    const int k0 = __builtin_amdgcn_readfirstlane(off[node]);
    const int k1 = __builtin_amdgcn_readfirstlane(off[node + 1]);
    const bool active = (DOUT == 64) || (lane < DOUT);
    float acc = active ? bvec[lane] : 0.f;
    int k = k0;
    for (; k + 3 < k1; k += 4) {
        int2 e0 = csr[k], e1 = csr[k + 1], e2 = csr[k + 2], e3 = csr[k + 3];
        int s0 = __builtin_amdgcn_readfirstlane(e0.x);
        int s1 = __builtin_amdgcn_readfirstlane(e1.x);
        int s2 = __builtin_amdgcn_readfirstlane(e2.x);
        int s3 = __builtin_amdgcn_readfirstlane(e3.x);
        float h0 = 0.f, h1 = 0.f, h2 = 0.f, h3 = 0.f;
        if (active) {
            h0 = __half2float(H[(size_t)s0 * DOUT + lane]);
            h1 = __half2float(H[(size_t)s1 * DOUT + lane]);
            h2 = __half2float(H[(size_t)s2 * DOUT + lane]);
            h3 = __half2float(H[(size_t)s3 * DOUT + lane]);
        }
        acc += h0 * __int_as_float(e0.y) + h1 * __int_as_float(e1.y)
             + h2 * __int_as_float(e2.y) + h3 * __int_as_float(e3.y);
    }
    for (; k < k1; ++k) {
        int2 e0 = csr[k];
        int s0 = __builtin_amdgcn_readfirstlane(e0.x);
        if (active) acc += __half2float(H[(size_t)s0 * DOUT + lane]) * __int_as_float(e0.y);
    }
    if (active) AGG[(size_t)node * DOUT + lane] = acc;
}

// ---------------------------------------------------------------------------
extern "C" void kernel_launch(void* const* d_in, const int* in_sizes, int n_in,
                              void* d_out, int out_size, void* d_ws, size_t ws_size,
                              hipStream_t stream) {
    const float* x    = (const float*)d_in[0];
    const float* ew   = (const float*)d_in[1];
    const float* W    = (const float*)d_in[2];   // [4,64,64]
    const float* b    = (const float*)d_in[3];   // [4,64]
    const float* Wout = (const float*)d_in[4];   // [64,40]
    const float* bout = (const float*)d_in[5];   // [40]
    const int*   src  = (const int*)d_in[6];
    const int*   dst  = (const int*)d_in[7];
    float* out = (float*)d_out;

    // workspace layout (tmp aliases H2: tmp fully consumed by build_csr
    // before the first gemm writes H2; stream order guarantees this)
    char* wsp = (char*)d_ws;
    __half* H2  = (__half*)wsp;                                   // N*64 half (12.8 MB)
    int2*   tmp = (int2*)wsp;                                     // E int2    (12.8 MB) alias
    size_t  o   = (size_t)N_NODES * 64 * sizeof(__half);
    float*  AGG = (float*)(wsp + o); o += (size_t)N_NODES * 64 * sizeof(float);
    int2*   csr = (int2*)(wsp + o);  o += (size_t)E_EDGES * sizeof(int2);
    int*    off = (int*)(wsp + o);   o += (size_t)(N_NODES + 1) * sizeof(int);
    int*  histM = (int*)(wsp + o);   o += (size_t)HM * sizeof(int);
    int*    hs  = (int*)(wsp + o);   o += (size_t)HM * sizeof(int);
    int*  bsums = (int*)(wsp + o);   o += (size_t)NSB * sizeof(int);
    int*   boff = (int*)(wsp + o);   o += (size_t)NSB * sizeof(int);

    dim3 blk(256);
    const int gemmGrid = (N_NODES + 63) / 64;              // 1563
    const int aggGrid  = (N_NODES * 64 + 255) / 256;       // 25000

    // ---- build CSR (once; reused by all 5 layers), zero global atomics ----
    chunk_hist<<<NCHUNK, blk, 0, stream>>>((const int4*)dst, histM);
    scan_blocks<<<NSB, blk, 0, stream>>>(histM, hs, bsums);
    scan_mid256<<<1, blk, 0, stream>>>(bsums, boff);
    scan_add<<<NSB, blk, 0, stream>>>(hs, boff);
    chunk_scatter<<<NCHUNK, blk, 0, stream>>>((const int4*)src, (const int4*)dst,
                                              (const float4*)ew, hs, tmp);
    build_csr<<<NBUCKETS, blk, 0, stream>>>(tmp, hs, off, csr);

    // ---- layer 0 ----
    gemm_tile<64, false><<<gemmGrid, blk, 0, stream>>>(x, W, H2);
    aggregate<64><<<aggGrid, blk, 0, stream>>>(H2, off, csr, b, AGG);

    // ---- layers 1..3 ----
    for (int i = 1; i < 4; ++i) {
        gemm_tile<64, true><<<gemmGrid, blk, 0, stream>>>(AGG, W + (size_t)i * 64 * 64, H2);
        aggregate<64><<<aggGrid, blk, 0, stream>>>(H2, off, csr, b + (size_t)i * 64, AGG);
    }

    // ---- final layer -> d_out [N,40] ----
    gemm_tile<40, true><<<gemmGrid, blk, 0, stream>>>(AGG, Wout, H2);
    aggregate<40><<<aggGrid, blk, 0, stream>>>(H2, off, csr, bout, out);
}